// Round 10
// baseline (1009.962 us; speedup 1.0000x reference)
//
#include <hip/hip_runtime.h>
#include <hip/hip_bf16.h>

typedef unsigned int u32;
typedef unsigned short u16;
typedef __bf16 bf16_t;
typedef bf16_t bf16x8 __attribute__((ext_vector_type(8)));
typedef float f32x4 __attribute__((ext_vector_type(4)));

constexpr int NN = 50000;
constexpr int EE = 500000;
constexpr int RR = 8;
constexpr int NKEY = RR * NN;               // 400000
constexpr int PAIR_B = (NKEY + 511) / 512;  // 782

// wext element offsets (bf16 elems)
constexpr int WX_A1T = 0;       // [64][128]
constexpr int WX_C1T = 8192;    // [128][256]
constexpr int WX_C2T = 40960;   // [128][128]
constexpr int WX_A2  = 57344;   // [64]
constexpr int WX_a1  = 57408;   // [64]
constexpr int WX_c1  = 57472;   // [128]
constexpr int WX_c2  = 57600;   // [128]
constexpr int WX_a2s = 57728;   // [1]
constexpr int WX_TOT = 57729;

__device__ __forceinline__ float bf2f(u32 v){
  union { u32 u; float f; } x; x.u = (v & 0xFFFFu) << 16; return x.f;
}
__device__ __forceinline__ u16 f2bf(float f){
  union { u32 u; float f; } x; x.f = f;
  u32 r = x.u + 0x7FFFu + ((x.u >> 16) & 1u);
  return (u16)(r >> 16);
}
__device__ __forceinline__ float lrelu(float x){ return x > 0.f ? x : 0.1f * x; }
__device__ __forceinline__ float ldf(const void* p, int i, u32 fm){
  return fm ? ((const float*)p)[i] : bf2f(((const u16*)p)[i]);
}

// ---------------- dtype detectors ----------------
__global__ void k_fdetect(const void* x, u32* md){
  __shared__ u32 c;
  if (threadIdx.x == 0) c = 0;
  __syncthreads();
  const u16* p = (const u16*)x;
  u32 loc = 0;
  for (int j = 0; j < 16; j++){
    u16 v = p[threadIdx.x * 16 + j];
    u32 e = (v >> 7) & 0xFF;
    if (e >= 0xFD) loc++;
  }
  atomicAdd(&c, loc);
  __syncthreads();
  if (threadIdx.x == 0) md[0] = (c >= 4) ? 1u : 0u;
}
__global__ void k_idetect(const void* et, u32* md){
  __shared__ u32 c;
  if (threadIdx.x == 0) c = 0;
  __syncthreads();
  const int* p = (const int*)et;
  u32 loc = 0;
  for (int j = 0; j < 8; j++){
    int idx = 2 * (threadIdx.x * 8 + j) + 1;
    if (p[idx] != 0) loc++;
  }
  atomicAdd(&c, loc);
  __syncthreads();
  if (threadIdx.x == 0) md[1] = (c == 0) ? 1u : 0u;
}

// ---------------- int conversion -> int32 ws copies
__global__ void k_icvt(const void* ei, const void* et, const void* bat,
                       int* ei_c, int* et_c, int* bat_c, const u32* md){
  u32 im = md[1];
  int i = blockIdx.x * 256 + threadIdx.x;
  if (i < 2 * EE){
    const int* p = (const int*)ei;
    ei_c[i] = im ? p[2 * i] : p[i];
  } else if (i < 3 * EE){
    int j = i - 2 * EE;
    const int* p = (const int*)et;
    et_c[j] = im ? p[2 * j] : p[j];
  } else if (i < 3 * EE + NN){
    int j = i - 3 * EE;
    const int* p = (const int*)bat;
    bat_c[j] = im ? p[2 * j] : p[j];
  }
}

// ---------------- x conversion -> bf16 ws copy (+NaN flag bit1)
__global__ void k_xcvt(const void* x, u16* xb, const u32* md, u32* flags){
  u32 fm = md[0];
  int i4 = (blockIdx.x * 256 + threadIdx.x) * 4;
  if (i4 >= NN * 128) return;
  float v[4];
  if (fm){
    float4 f = *(const float4*)((const float*)x + i4);
    v[0]=f.x; v[1]=f.y; v[2]=f.z; v[3]=f.w;
  } else {
    uint2 u = *(const uint2*)((const u16*)x + i4);
    v[0]=bf2f(u.x); v[1]=bf2f(u.x>>16); v[2]=bf2f(u.y); v[3]=bf2f(u.y>>16);
  }
  bool bad = false;
  u16 o[4];
  for (int j = 0; j < 4; j++){
    if (v[j] != v[j]){ bad = true; v[j] = 0.f; }
    o[j] = f2bf(v[j]);
  }
  unsigned long long bal = __ballot(bad);
  if (bal && (threadIdx.x & 63) == 0) atomicOr(flags, 2u);
  uint2 st;
  st.x = (u32)o[0] | ((u32)o[1] << 16);
  st.y = (u32)o[2] | ((u32)o[3] << 16);
  *(uint2*)(xb + i4) = st;
}

// ---------------- weight transpose: wcatT[L][n][k]; k<1024 -> W[L][k][n], else root[k-1024][n]
__global__ void k_wcat(const void* W1, const void* r1, const void* W2, const void* r2,
                       const void* W3, const void* r3, u16* wcatT, const u32* md, u32* flags){
  u32 fm = md[0];
  int idx = blockIdx.x * 256 + threadIdx.x;
  if (idx >= 3 * 128 * 1152) return;
  int L = idx / (128 * 1152);
  int rem = idx % (128 * 1152);
  int n = rem / 1152, k = rem % 1152;
  const void* W  = (L == 0) ? W1 : ((L == 1) ? W2 : W3);
  const void* rt = (L == 0) ? r1 : ((L == 1) ? r2 : r3);
  float v = (k < 1024) ? ldf(W, k * 128 + n, fm) : ldf(rt, (k - 1024) * 128 + n, fm);
  if (v != v){ v = 0.f; atomicOr(flags, 2u); }
  wcatT[idx] = f2bf(v);
}

// ---------------- small-MLP weight prep
__global__ void k_wext(const void* A1, const void* a1, const void* A2, const void* a2,
                       const void* C1, const void* c1, const void* C2, const void* c2,
                       u16* wext, const u32* md){
  u32 fm = md[0];
  int idx = blockIdx.x * 256 + threadIdx.x;
  if (idx >= WX_TOT) return;
  float v;
  if (idx < WX_C1T){
    int n = idx >> 7, k = idx & 127;
    v = ldf(A1, k * 64 + n, fm);
  } else if (idx < WX_C2T){
    int j = idx - WX_C1T; int n = j >> 8, k = j & 255;
    v = ldf(C1, k * 128 + n, fm);
  } else if (idx < WX_A2){
    int j = idx - WX_C2T; int n = j >> 7, k = j & 127;
    v = ldf(C2, k * 128 + n, fm);
  } else if (idx < WX_a1){ v = ldf(A2, idx - WX_A2, fm); }
  else if (idx < WX_c1){ v = ldf(a1, idx - WX_a1, fm); }
  else if (idx < WX_c2){ v = ldf(c1, idx - WX_c1, fm); }
  else if (idx < WX_a2s){ v = ldf(c2, idx - WX_c2, fm); }
  else { v = ldf(a2, 0, fm); }
  wext[idx] = f2bf(v);
}

// ---------------- (rel,dst) counting sort ----------------
__global__ void k_count3(const int* __restrict__ ei, const int* __restrict__ et, u32* __restrict__ cnt){
  int e = blockIdx.x * 256 + threadIdx.x;
  if (e >= EE) return;
  atomicAdd(&cnt[ei[EE + e] * RR + et[e]], 1u);
}
__global__ void k_pairA(const u32* __restrict__ cnt, u32* __restrict__ blockSum){
  __shared__ u32 sd[256];
  int b = blockIdx.x, t = threadIdx.x;
  u32 s = 0;
  for (int j = 0; j < 2; j++){
    int key = b * 512 + t * 2 + j;
    if (key < NKEY){ int r = key / NN, d = key % NN; s += cnt[d * RR + r]; }
  }
  sd[t] = s; __syncthreads();
  for (int off = 128; off; off >>= 1){ if (t < off) sd[t] += sd[t + off]; __syncthreads(); }
  if (t == 0) blockSum[b] = sd[0];
}
__global__ void k_pairB(const u32* __restrict__ blockSum, u32* __restrict__ blockBase){
  int lane = threadIdx.x;   // 64
  u32 loc[13]; u32 s = 0;
  for (int j = 0; j < 13; j++){
    int b = lane * 13 + j;
    u32 v = (b < PAIR_B) ? blockSum[b] : 0u;
    loc[j] = s; s += v;
  }
  u32 tot = s;
  for (int off = 1; off < 64; off <<= 1){
    u32 x = __shfl_up(tot, off);
    if (lane >= off) tot += x;
  }
  u32 excl = tot - s;
  for (int j = 0; j < 13; j++){
    int b = lane * 13 + j;
    if (b < PAIR_B) blockBase[b] = excl + loc[j];
  }
}
__global__ void k_pairC(const u32* __restrict__ cnt, const u32* __restrict__ blockBase,
                        u32* __restrict__ pairStart, u32* __restrict__ cursor){
  __shared__ u32 sd[256];
  int b = blockIdx.x, t = threadIdx.x;
  int k0 = b * 512 + t * 2;
  u32 v0 = 0, v1 = 0;
  if (k0 < NKEY){ int r = k0 / NN, d = k0 % NN; v0 = cnt[d * RR + r]; }
  if (k0 + 1 < NKEY){ int r = (k0 + 1) / NN, d = (k0 + 1) % NN; v1 = cnt[d * RR + r]; }
  sd[t] = v0 + v1; __syncthreads();
  for (int off = 1; off < 256; off <<= 1){
    u32 x = (t >= off) ? sd[t - off] : 0u;
    __syncthreads();
    sd[t] += x;
    __syncthreads();
  }
  u32 excl = sd[t] - (v0 + v1);
  u32 base = blockBase[b] + excl;
  if (k0 < NKEY){ pairStart[k0] = base; cursor[k0] = 0u; }
  if (k0 + 1 < NKEY){ pairStart[k0 + 1] = base + v0; cursor[k0 + 1] = 0u; }
}
__global__ void k_reloff(u32* __restrict__ pairStart, u32* __restrict__ relOff){
  int t = threadIdx.x;
  if (t < RR) relOff[t] = pairStart[t * NN];
  if (t == RR){ relOff[RR] = (u32)EE; pairStart[NKEY] = (u32)EE; }
}
__global__ void k_sort3(const int* __restrict__ ei, const int* __restrict__ et,
                        const u32* __restrict__ pairStart, u32* __restrict__ cursor,
                        u32* __restrict__ src_s){
  int e = blockIdx.x * 256 + threadIdx.x;
  if (e >= EE) return;
  int r = et[e], d = ei[EE + e];
  u32 key = (u32)r * NN + (u32)d;
  u32 p = pairStart[key] + atomicAdd(&cursor[key], 1u);
  src_s[p] = (u32)ei[e];
}

// ---------------- fused GEMM: out[N,128] = [mean-agg(h) | h] (K=1152) @ wcatT + bias
// agg is computed inline during A-staging: for k<1024, r=k>>7, key=(r,node) segment
// gather of h via pairStart/src_s (each key belongs to exactly one block-row).
#define PADE 8
__global__ __launch_bounds__(256) void k_gemm_fused(const u16* __restrict__ h,
                                                    const u32* __restrict__ pairStart,
                                                    const u32* __restrict__ src_s,
                                                    const u16* __restrict__ wT,
                                                    const void* __restrict__ bias,
                                                    float* __restrict__ out, const u32* md){
  __shared__ u16 As[128][64 + PADE];
  __shared__ u16 Bs[128][64 + PADE];
  u32 fm = md[0];
  int m0 = blockIdx.x * 128;
  int tid = threadIdx.x;
  int w = tid >> 6, lane = tid & 63, qd = lane >> 4, l16 = lane & 15;
  f32x4 acc[2][8];
  for (int i = 0; i < 2; i++) for (int j = 0; j < 8; j++) acc[i][j] = (f32x4){0.f,0.f,0.f,0.f};
  for (int k0 = 0; k0 < 1152; k0 += 64){
    __syncthreads();
    for (int it = 0; it < 4; it++){
      int lin = it * 2048 + tid * 8;
      int row = lin >> 6, kl = lin & 63;
      int node = m0 + row;
      int k = k0 + kl;
      uint4 v = make_uint4(0u,0u,0u,0u);
      if (node < NN){
        if (k < 1024){
          int r = k >> 7;
          int dim = k & 127;           // 8-aligned, chunk stays within one relation
          u32 key = (u32)r * NN + (u32)node;
          u32 s = pairStart[key], e = pairStart[key + 1];
          if (e > s){
            float a0=0.f,a1=0.f,a2=0.f,a3=0.f,a4=0.f,a5=0.f,a6=0.f,a7=0.f;
            for (u32 j = s; j < e; j++){
              u32 src = src_s[j];
              uint4 hv = *(const uint4*)(h + (size_t)src * 128 + dim);
              a0 += bf2f(hv.x); a1 += bf2f(hv.x >> 16);
              a2 += bf2f(hv.y); a3 += bf2f(hv.y >> 16);
              a4 += bf2f(hv.z); a5 += bf2f(hv.z >> 16);
              a6 += bf2f(hv.w); a7 += bf2f(hv.w >> 16);
            }
            float sc = 1.0f / (float)(e - s);
            v.x = (u32)f2bf(a0 * sc) | ((u32)f2bf(a1 * sc) << 16);
            v.y = (u32)f2bf(a2 * sc) | ((u32)f2bf(a3 * sc) << 16);
            v.z = (u32)f2bf(a4 * sc) | ((u32)f2bf(a5 * sc) << 16);
            v.w = (u32)f2bf(a6 * sc) | ((u32)f2bf(a7 * sc) << 16);
          }
        } else {
          v = *(const uint4*)(h + (size_t)node * 128 + (k - 1024));
        }
      }
      *(uint4*)(&As[row][kl]) = v;
      uint4 b = *(const uint4*)(wT + (size_t)row * 1152 + k0 + kl);
      *(uint4*)(&Bs[row][kl]) = b;
    }
    __syncthreads();
    for (int kk = 0; kk < 64; kk += 32){
      bf16x8 a[2], bf[8];
      for (int rt = 0; rt < 2; rt++) a[rt] = *(const bf16x8*)(&As[w * 32 + rt * 16 + l16][kk + qd * 8]);
      for (int ct = 0; ct < 8; ct++) bf[ct] = *(const bf16x8*)(&Bs[ct * 16 + l16][kk + qd * 8]);
      for (int rt = 0; rt < 2; rt++)
        for (int ct = 0; ct < 8; ct++)
          acc[rt][ct] = __builtin_amdgcn_mfma_f32_16x16x32_bf16(a[rt], bf[ct], acc[rt][ct], 0, 0, 0);
    }
  }
  for (int rt = 0; rt < 2; rt++){
    int rbase = m0 + w * 32 + rt * 16 + qd * 4;
    for (int ct = 0; ct < 8; ct++){
      int col = ct * 16 + l16;
      float bv = ldf(bias, col, fm);
      for (int rg = 0; rg < 4; rg++){
        int node = rbase + rg;
        if (node < NN) out[node * 128 + col] = acc[rt][ct][rg] + bv;
      }
    }
  }
}

// ---------------- BatchNorm (391 blocks × 128 rows)
__global__ void k_bnstats(const float* __restrict__ out, float* __restrict__ stats){
  __shared__ float sb[256], sb2[256];
  int tid = threadIdx.x;
  int col = tid & 127, half = tid >> 7;
  int r0 = blockIdx.x * 128;
  float s = 0.f, s2 = 0.f;
  for (int i = half; i < 128; i += 2){
    int n = r0 + i;
    if (n < NN){ float v = out[n * 128 + col]; s += v; s2 += v * v; }
  }
  sb[tid] = s; sb2[tid] = s2;
  __syncthreads();
  if (half == 0){
    unsafeAtomicAdd(&stats[col],       sb[col] + sb[col + 128]);
    unsafeAtomicAdd(&stats[128 + col], sb2[col] + sb2[col + 128]);
  }
}

__global__ void k_bnapply(const float* __restrict__ out, const float* __restrict__ stats,
                          const void* __restrict__ g, const void* __restrict__ beta,
                          u16* __restrict__ hout, const u32* md, u32* flags, u32 layerbit){
  u32 fm = md[0];
  int idx = (blockIdx.x * 256 + threadIdx.x) * 4;
  if (idx >= NN * 128) return;
  int col = idx & 127;
  float4 v = *(const float4*)(out + idx);
  float vv[4] = {v.x, v.y, v.z, v.w};
  bool bad = false;
  u16 o[4];
  for (int j = 0; j < 4; j++){
    int c = col + j;
    float mu = stats[c] * (1.0f / NN);
    float var = fmaxf(stats[128 + c] * (1.0f / NN) - mu * mu, 0.f);
    float sc = ldf(g, c, fm) * rsqrtf(var + 1e-5f);
    float sh = ldf(beta, c, fm) - mu * sc;
    float r = vv[j] * sc + sh;
    if (r != r || sc != sc){ bad = true; r = 0.f; }
    o[j] = f2bf(lrelu(r));
  }
  unsigned long long bal = __ballot(bad);
  if (bal && (threadIdx.x & 63) == 0) atomicOr(flags, layerbit);
  uint2 st;
  st.x = (u32)o[0] | ((u32)o[1] << 16);
  st.y = (u32)o[2] | ((u32)o[3] << 16);
  *(uint2*)(hout + idx) = st;
}

// ---------------- attention scores via MFMA
__global__ __launch_bounds__(256) void k_scores_mfma(const float* __restrict__ emb,
                                                     const u16* __restrict__ wext,
                                                     float* __restrict__ scores){
  __shared__ u16 As[128][136];
  int m0 = blockIdx.x * 128;
  int tid = threadIdx.x;
  int w = tid >> 6, lane = tid & 63, qd = lane >> 4, l16 = lane & 15;
  for (int it = 0; it < 16; it++){
    int lin = it * 1024 + tid * 4;
    int row = lin >> 7, c = lin & 127;
    int node = m0 + row;
    float4 v = make_float4(0.f,0.f,0.f,0.f);
    if (node < NN) v = *(const float4*)(emb + (size_t)node * 128 + c);
    uint2 st;
    st.x = (u32)f2bf(v.x) | ((u32)f2bf(v.y) << 16);
    st.y = (u32)f2bf(v.z) | ((u32)f2bf(v.w) << 16);
    *(uint2*)(&As[row][c]) = st;
  }
  __syncthreads();
  f32x4 acc[2][4];
  for (int i = 0; i < 2; i++) for (int j = 0; j < 4; j++) acc[i][j] = (f32x4){0.f,0.f,0.f,0.f};
  for (int k0 = 0; k0 < 4; k0++){
    bf16x8 a[2];
    a[0] = *(const bf16x8*)(&As[(w * 2) * 16 + l16][k0 * 32 + qd * 8]);
    a[1] = *(const bf16x8*)(&As[(w * 2 + 1) * 16 + l16][k0 * 32 + qd * 8]);
    for (int ct = 0; ct < 4; ct++){
      bf16x8 b = *(const bf16x8*)(wext + WX_A1T + (size_t)(ct * 16 + l16) * 128 + k0 * 32 + qd * 8);
      acc[0][ct] = __builtin_amdgcn_mfma_f32_16x16x32_bf16(a[0], b, acc[0][ct], 0, 0, 0);
      acc[1][ct] = __builtin_amdgcn_mfma_f32_16x16x32_bf16(a[1], b, acc[1][ct], 0, 0, 0);
    }
  }
  float a1v[4], a2v[4];
  for (int ct = 0; ct < 4; ct++){
    a1v[ct] = bf2f(wext[WX_a1 + ct * 16 + l16]);
    a2v[ct] = bf2f(wext[WX_A2 + ct * 16 + l16]);
  }
  float a2s = bf2f(wext[WX_a2s]);
  for (int rt = 0; rt < 2; rt++)
    for (int rg = 0; rg < 4; rg++){
      float s = 0.f;
      for (int ct = 0; ct < 4; ct++)
        s += lrelu(acc[rt][ct][rg] + a1v[ct]) * a2v[ct];
      s += __shfl_xor(s, 1); s += __shfl_xor(s, 2);
      s += __shfl_xor(s, 4); s += __shfl_xor(s, 8);
      int row = m0 + (w * 2 + rt) * 16 + qd * 4 + rg;
      if (l16 == 0 && row < NN) scores[row] = s + a2s;
    }
}

__device__ __forceinline__ u32 fmap(float f){
  union{u32 u; float f;} x; x.f = f;
  return (x.u & 0x80000000u) ? ~x.u : (x.u | 0x80000000u);
}
__device__ __forceinline__ float funmap(u32 m){
  union{u32 u; float f;} x;
  x.u = (m & 0x80000000u) ? (m ^ 0x80000000u) : ~m;
  return x.f;
}

__global__ void k_max(const float* __restrict__ scores, u32* smax){
  int gid = blockIdx.x * 256 + threadIdx.x;
  float m = -1e30f;
  for (int i = gid; i < NN; i += 256 * 128) m = fmaxf(m, scores[i]);
  for (int off = 32; off; off >>= 1) m = fmaxf(m, __shfl_down(m, off));
  if ((threadIdx.x & 63) == 0) atomicMax(smax, fmap(m));
}

__global__ void k_expsum(const float* __restrict__ scores, const u32* smax,
                         float* __restrict__ attnw, float* ssum, u32* flags){
  float mx = funmap(*smax);
  int gid = blockIdx.x * 256 + threadIdx.x;
  if (mx != mx){ if (gid == 0) atomicOr(flags, 32u); mx = 0.f; }
  float s = 0.f;
  bool bad = false;
  for (int i = gid; i < NN; i += 256 * 128){
    float e = __expf(scores[i] - mx);
    if (e != e){ bad = true; e = 0.f; }
    attnw[i] = e; s += e;
  }
  unsigned long long bal = __ballot(bad);
  if (bal && (threadIdx.x & 63) == 0) atomicOr(flags, 32u);
  for (int off = 32; off; off >>= 1) s += __shfl_down(s, off);
  if ((threadIdx.x & 63) == 0) unsafeAtomicAdd(ssum, s);
}

// ---------------- pooling: 32 nodes/block, per-run atomics (1563 blocks)
constexpr int POOL_CHUNK = 32;
__global__ __launch_bounds__(128) void k_pool(const float* __restrict__ emb,
                                              const float* __restrict__ attnw,
                                              const float* __restrict__ ssum,
                                              const int* __restrict__ batch,
                                              float* __restrict__ gemb, u32* flags){
  int t = threadIdx.x;
  int n0 = blockIdx.x * POOL_CHUNK;
  if (n0 >= NN) return;
  int n1 = min(n0 + POOL_CHUNK, NN);
  float sv = *ssum;
  bool bad = !(sv > 0.f) || (sv != sv);
  if (bad && t == 0 && blockIdx.x == 0) atomicOr(flags, 64u);
  float rs = bad ? 0.f : 1.0f / sv;
  int cur = batch[n0];
  float acc = 0.f;
  for (int n = n0; n < n1; n++){
    int b = batch[n];
    if (b != cur){ unsafeAtomicAdd(&gemb[cur * 128 + t], acc * rs); acc = 0.f; cur = b; }
    acc += emb[(size_t)n * 128 + t] * attnw[n];
  }
  unsafeAtomicAdd(&gemb[cur * 128 + t], acc * rs);
}

// ---------------- final combiner via MFMA + row L2 normalize
__global__ __launch_bounds__(256) void k_final_mfma(const float* __restrict__ emb,
                                                    const float* __restrict__ gemb,
                                                    const int* __restrict__ batch,
                                                    const u16* __restrict__ wext,
                                                    void* __restrict__ outp,
                                                    const u32* md){
  __shared__ u16 As[128][264];
  u16 (*Hs)[136] = (u16(*)[136])(&As[0][0]);
  u32 fm = md[0];
  int m0 = blockIdx.x * 128;
  int tid = threadIdx.x;
  int w = tid >> 6, lane = tid & 63, qd = lane >> 4, l16 = lane & 15;
  for (int it = 0; it < 32; it++){
    int lin = it * 1024 + tid * 4;
    int row = lin >> 8, c = lin & 255;
    int node = m0 + row;
    float4 v = make_float4(0.f,0.f,0.f,0.f);
    if (node < NN){
      if (c < 128) v = *(const float4*)(emb + (size_t)node * 128 + c);
      else { int g = batch[node]; v = *(const float4*)(gemb + (size_t)g * 128 + (c - 128)); }
    }
    uint2 st;
    st.x = (u32)f2bf(v.x) | ((u32)f2bf(v.y) << 16);
    st.y = (u32)f2bf(v.z) | ((u32)f2bf(v.w) << 16);
    *(uint2*)(&As[row][c]) = st;
  }
  __syncthreads();
  f32x4 acc[2][8];
  for (int i = 0; i < 2; i++) for (int j = 0; j < 8; j++) acc[i][j] = (f32x4){0.f,0.f,0.f,0.f};
  for (int k0 = 0; k0 < 8; k0++){
    bf16x8 a[2];
    a[0] = *(const bf16x8*)(&As[(w * 2) * 16 + l16][k0 * 32 + qd * 8]);
    a[1] = *(const bf16x8*)(&As[(w * 2 + 1) * 16 + l16][k0 * 32 + qd * 8]);
    for (int ct = 0; ct < 8; ct++){
      bf16x8 b = *(const bf16x8*)(wext + WX_C1T + (size_t)(ct * 16 + l16) * 256 + k0 * 32 + qd * 8);
      acc[0][ct] = __builtin_amdgcn_mfma_f32_16x16x32_bf16(a[0], b, acc[0][ct], 0, 0, 0);
      acc[1][ct] = __builtin_amdgcn_mfma_f32_16x16x32_bf16(a[1], b, acc[1][ct], 0, 0, 0);
    }
  }
  __syncthreads();
  for (int rt = 0; rt < 2; rt++)
    for (int ct = 0; ct < 8; ct++){
      float c1v = bf2f(wext[WX_c1 + ct * 16 + l16]);
      for (int rg = 0; rg < 4; rg++){
        int row = (w * 2 + rt) * 16 + qd * 4 + rg;
        Hs[row][ct * 16 + l16] = f2bf(lrelu(acc[rt][ct][rg] + c1v));
      }
    }
  __syncthreads();
  f32x4 acc2[2][8];
  for (int i = 0; i < 2; i++) for (int j = 0; j < 8; j++) acc2[i][j] = (f32x4){0.f,0.f,0.f,0.f};
  for (int k0 = 0; k0 < 4; k0++){
    bf16x8 a[2];
    a[0] = *(const bf16x8*)(&Hs[(w * 2) * 16 + l16][k0 * 32 + qd * 8]);
    a[1] = *(const bf16x8*)(&Hs[(w * 2 + 1) * 16 + l16][k0 * 32 + qd * 8]);
    for (int ct = 0; ct < 8; ct++){
      bf16x8 b = *(const bf16x8*)(wext + WX_C2T + (size_t)(ct * 16 + l16) * 128 + k0 * 32 + qd * 8);
      acc2[0][ct] = __builtin_amdgcn_mfma_f32_16x16x32_bf16(a[0], b, acc2[0][ct], 0, 0, 0);
      acc2[1][ct] = __builtin_amdgcn_mfma_f32_16x16x32_bf16(a[1], b, acc2[1][ct], 0, 0, 0);
    }
  }
  float c2v[8];
  for (int ct = 0; ct < 8; ct++) c2v[ct] = bf2f(wext[WX_c2 + ct * 16 + l16]);
  for (int rt = 0; rt < 2; rt++)
    for (int rg = 0; rg < 4; rg++){
      float ss = 0.f;
      for (int ct = 0; ct < 8; ct++){
        float o = acc2[rt][ct][rg] + c2v[ct];
        ss += o * o;
      }
      ss += __shfl_xor(ss, 1); ss += __shfl_xor(ss, 2);
      ss += __shfl_xor(ss, 4); ss += __shfl_xor(ss, 8);
      float sc = 1.0f / fmaxf(sqrtf(ss), 1e-12f);
      int row = m0 + (w * 2 + rt) * 16 + qd * 4 + rg;
      if (row < NN){
        if (fm){
          float* op = (float*)outp;
          for (int ct = 0; ct < 8; ct++)
            op[(size_t)row * 128 + ct * 16 + l16] = (acc2[rt][ct][rg] + c2v[ct]) * sc;
        } else {
          u16* op = (u16*)outp;
          for (int ct = 0; ct < 8; ct++)
            op[(size_t)row * 128 + ct * 16 + l16] = f2bf((acc2[rt][ct][rg] + c2v[ct]) * sc);
        }
      }
    }
}

// ---------------- diag sentinels
__global__ void k_diag(const u32* relOff, const u32* flags, const u32* md, void* outp){
  if (threadIdx.x != 0 || blockIdx.x != 0) return;
  u32 fm = md[0];
  u32 f = flags[0];
  if (relOff[RR] != (u32)EE) f |= 1u;
  for (int b = 0; b < 9; b++){
    if (f & (1u << b)){
      float s = (float)(131072 >> b);
      if (fm) ((float*)outp)[b] = s;
      else ((u16*)outp)[b] = f2bf(s);
    }
  }
}
__global__ void k_wsfail(u32* outp){ outp[0] = 0x43000000u; }

// ---------------- workspace layout (bytes)
constexpr size_t O_OUT   = 0;          // f32 N*128; pre-GEMM aliases: cursor/blockSum/blockBase
constexpr size_t O_H     = 25600000;
constexpr size_t O_XBF   = 38400000;
constexpr size_t O_WCAT  = 51200000;
constexpr size_t O_WEXT  = 52084736;
constexpr size_t O_EI    = 52200448;
constexpr size_t O_ET    = 56200448;
constexpr size_t O_BAT   = 58200448;
constexpr size_t O_SRC   = 58400448;   // 2 MB (src_s)
constexpr size_t O_PST   = 60400448;   // pairStart: (NKEY+1) u32
constexpr size_t O_CNT   = 62400448;   // 1.6 MB
constexpr size_t O_SCO   = 65600448;
constexpr size_t O_AW    = 65800448;
constexpr size_t O_GEMB  = 66000448;
constexpr size_t O_STATS = 66033216;
constexpr size_t O_MISC  = 66035264;
constexpr size_t WS_NEED = 66035520;

extern "C" void kernel_launch(void* const* d_in, const int* in_sizes, int n_in,
                              void* d_out, int out_size, void* d_ws, size_t ws_size,
                              hipStream_t stream) {
  const void* x     = d_in[0];
  const void* ei    = d_in[1];
  const void* et    = d_in[2];
  const void* batch = d_in[3];
  const void* W1 = d_in[4],  *r1 = d_in[5],  *b1 = d_in[6];
  const void* W2 = d_in[7],  *r2 = d_in[8],  *b2 = d_in[9];
  const void* W3 = d_in[10], *r3 = d_in[11], *b3 = d_in[12];
  const void* g1 = d_in[13], *be1 = d_in[14];
  const void* g2 = d_in[15], *be2 = d_in[16];
  const void* A1 = d_in[17], *a1 = d_in[18];
  const void* A2 = d_in[19], *a2 = d_in[20];
  const void* C1 = d_in[21], *c1 = d_in[22];
  const void* C2 = d_in[23], *c2 = d_in[24];

  if (ws_size < WS_NEED){ k_wsfail<<<1, 1, 0, stream>>>((u32*)d_out); return; }
  char* ws = (char*)d_ws;
  float* out   = (float*)(ws + O_OUT);
  u16*   hbuf  = (u16*)(ws + O_H);
  u16*   xbf   = (u16*)(ws + O_XBF);
  u16*   wcat  = (u16*)(ws + O_WCAT);
  u16*   wext  = (u16*)(ws + O_WEXT);
  int*   ei_c  = (int*)(ws + O_EI);
  int*   et_c  = (int*)(ws + O_ET);
  int*   bat_c = (int*)(ws + O_BAT);
  u32*   src_s = (u32*)(ws + O_SRC);
  u32*   pairStart = (u32*)(ws + O_PST);
  u32*   cnt   = (u32*)(ws + O_CNT);
  float* sco   = (float*)(ws + O_SCO);
  float* aw    = (float*)(ws + O_AW);
  float* gemb  = (float*)(ws + O_GEMB);
  float* stats = (float*)(ws + O_STATS);
  u32*   misc  = (u32*)(ws + O_MISC);
  u32* cursor    = (u32*)(ws + O_OUT);
  u32* blockSum  = (u32*)(ws + O_OUT + 1600000);
  u32* blockBase = (u32*)(ws + O_OUT + 1604096);
  u32* relOff = misc + 16;
  u32* smax = misc + 25;
  float* ssum = (float*)(misc + 26);
  u32* flags = misc + 27;
  u32* md = misc + 28;

  hipMemsetAsync(ws + O_CNT, 0, 1600000, stream);
  hipMemsetAsync(ws + O_GEMB, 0, 32768 + 2048 + 256, stream);

  k_fdetect<<<1, 256, 0, stream>>>(x, md);
  k_idetect<<<1, 256, 0, stream>>>(et, md);
  k_icvt<<<6055, 256, 0, stream>>>(ei, et, batch, ei_c, et_c, bat_c, md);
  k_xcvt<<<6250, 256, 0, stream>>>(x, xbf, md, flags);
  k_wcat<<<1728, 256, 0, stream>>>(W1, r1, W2, r2, W3, r3, wcat, md, flags);
  k_wext<<<227, 256, 0, stream>>>(A1, a1, A2, a2, C1, c1, C2, c2, wext, md);

  k_count3<<<(EE + 255) / 256, 256, 0, stream>>>(ei_c, et_c, cnt);
  k_pairA<<<PAIR_B, 256, 0, stream>>>(cnt, blockSum);
  k_pairB<<<1, 64, 0, stream>>>(blockSum, blockBase);
  k_pairC<<<PAIR_B, 256, 0, stream>>>(cnt, blockBase, pairStart, cursor);
  k_reloff<<<1, 64, 0, stream>>>(pairStart, relOff);
  k_sort3<<<(EE + 255) / 256, 256, 0, stream>>>(ei_c, et_c, pairStart, cursor, src_s);

  const void* bias[3] = {b1, b2, b3};
  const void* gam[2] = {g1, g2};
  const void* bet[2] = {be1, be2};
  const u16* hin = xbf;
  for (int L = 0; L < 3; L++){
    const u16* wT = wcat + (size_t)L * 128 * 1152;
    k_gemm_fused<<<391, 256, 0, stream>>>(hin, pairStart, src_s, wT, bias[L], out, md);
    if (L < 2){
      k_bnstats<<<391, 256, 0, stream>>>(out, stats + L * 256);
      k_bnapply<<<6250, 256, 0, stream>>>(out, stats + L * 256, gam[L], bet[L], hbuf, md, flags, 4u << L);
      hin = hbuf;
    }
  }
  k_scores_mfma<<<391, 256, 0, stream>>>(out, wext, sco);
  k_max<<<128, 256, 0, stream>>>(sco, smax);
  k_expsum<<<128, 256, 0, stream>>>(sco, smax, aw, ssum, flags);
  k_pool<<<(NN + POOL_CHUNK - 1) / POOL_CHUNK, 128, 0, stream>>>(out, aw, ssum, bat_c, gemb, flags);
  k_final_mfma<<<391, 256, 0, stream>>>(out, gemb, bat_c, wext, d_out, md);
  k_diag<<<1, 64, 0, stream>>>(relOff, flags, md, d_out);
}